// Round 10
// baseline (398.952 us; speedup 1.0000x reference)
//
#include <hip/hip_runtime.h>

typedef _Float16 half8 __attribute__((ext_vector_type(8)));
typedef _Float16 half4v __attribute__((ext_vector_type(4)));
typedef float f32x4 __attribute__((ext_vector_type(4)));

#define NB 4
#define SQ 512
#define CL 3584
#define TT 4096
#define DM 2048
#define NH 16
#define DH 128

// XOR swizzles on half-index (attn LDS)
#define KSW(row, col) ((((row) * 128) + (col)) ^ ((((row) & 7) << 3)))
#define VSW(row, col) ((((row) * 64) + (col)) ^ ((((row) & 7) << 3)))

__device__ __forceinline__ void gl_lds16(const void* g, void* l) {
  __builtin_amdgcn_global_load_lds(
      (const __attribute__((address_space(1))) unsigned int*)g,
      (__attribute__((address_space(3))) unsigned int*)l, 16, 0, 0);
}

// ---------------- generic fp32 -> f16 convert (3 segments, strided dst) ----------------
__global__ __launch_bounds__(256) void cvt_f16(
    const float* __restrict__ s0, const float* __restrict__ s1, const float* __restrict__ s2,
    _Float16* __restrict__ d0, _Float16* __restrict__ d1, _Float16* __restrict__ d2,
    int dstride)
{
  const float* s = blockIdx.y == 0 ? s0 : blockIdx.y == 1 ? s1 : s2;
  _Float16* d = blockIdx.y == 0 ? d0 : blockIdx.y == 1 ? d1 : d2;
  const int n4 = DM * DM / 4;
  for (int v = blockIdx.x * blockDim.x + threadIdx.x; v < n4;
       v += gridDim.x * blockDim.x) {
    float4 x = ((const float4*)s)[v];
    half4v h = { (_Float16)x.x, (_Float16)x.y, (_Float16)x.z, (_Float16)x.w };
    const int m = v >> 9, c = (v << 2) & 2047;
    *(half4v*)&d[(size_t)m * dstride + c] = h;
  }
}

// ---------------- cached K fp32 -> f16 linear convert ----------------
__global__ __launch_bounds__(256) void convert_K(
    const float* __restrict__ ck, _Float16* __restrict__ K)
{
  const long long nvec = (long long)NB * CL * DM / 4;
  const int pb = CL * DM / 4;
  for (long long v = (long long)blockIdx.x * blockDim.x + threadIdx.x; v < nvec;
       v += (long long)gridDim.x * blockDim.x) {
    int b = (int)(v / pb);
    long long r = v - (long long)b * pb;
    float4 x = ((const float4*)ck)[v];
    half4v hx = { (_Float16)x.x, (_Float16)x.y, (_Float16)x.z, (_Float16)x.w };
    ((half4v*)K)[(long long)b * (TT * DM / 4) + r] = hx;
  }
}

// ---------------- cached V fp32 -> f16 transpose: Vt[b][h][d][t] ----------------
__global__ __launch_bounds__(256) void transpose_V(
    const float* __restrict__ cv, _Float16* __restrict__ Vt)
{
  __shared__ _Float16 T[64][72];
  const int t0 = blockIdx.x * 64;
  const int dm0 = blockIdx.y * 64;
  const int b = blockIdx.z;
  const int tid = threadIdx.x;
  {
    const int tr = tid >> 2, c0 = (tid & 3) * 16;
    const float* src = cv + ((size_t)b * CL + t0 + tr) * DM + dm0 + c0;
    float4 a0 = ((const float4*)src)[0];
    float4 a1 = ((const float4*)src)[1];
    float4 a2 = ((const float4*)src)[2];
    float4 a3 = ((const float4*)src)[3];
    half8 h0 = { (_Float16)a0.x, (_Float16)a0.y, (_Float16)a0.z, (_Float16)a0.w,
                 (_Float16)a1.x, (_Float16)a1.y, (_Float16)a1.z, (_Float16)a1.w };
    half8 h1 = { (_Float16)a2.x, (_Float16)a2.y, (_Float16)a2.z, (_Float16)a2.w,
                 (_Float16)a3.x, (_Float16)a3.y, (_Float16)a3.z, (_Float16)a3.w };
    *(half8*)&T[tr][c0] = h0;
    *(half8*)&T[tr][c0 + 8] = h1;
  }
  __syncthreads();
  {
    const int dl = tid >> 2, tc = (tid & 3) * 16;
    const int h = dm0 >> 7, d = (dm0 & 127) + dl;
    half8 o0, o1;
#pragma unroll
    for (int i = 0; i < 8; ++i) o0[i] = T[tc + i][dl];
#pragma unroll
    for (int i = 0; i < 8; ++i) o1[i] = T[tc + 8 + i][dl];
    _Float16* dst = Vt + ((size_t)(b * NH + h) * DH + d) * TT + t0 + tc;
    *(half8*)dst = o0;
    *(half8*)(dst + 8) = o1;
  }
}

// ---------------- f16 GEMM via global_load_lds (unchanged from R4) ----------------
template<int MODE>
__global__ __launch_bounds__(512, 4) void mm16(
    const _Float16* __restrict__ A0, const _Float16* __restrict__ A1,
    const _Float16* __restrict__ A2, int astride,
    const _Float16* __restrict__ W0, const _Float16* __restrict__ W1,
    const _Float16* __restrict__ W2,
    const float* __restrict__ b0, const float* __restrict__ b1,
    const float* __restrict__ b2,
    _Float16* __restrict__ Qp, _Float16* __restrict__ Kc,
    _Float16* __restrict__ Vt, float* __restrict__ Co)
{
  __shared__ __align__(16) char smem[4 * 8192];
  char* Abuf = smem;
  char* Wbuf = smem + 2 * 8192;

  const int tid = threadIdx.x;
  const int bm = blockIdx.x, bn = blockIdx.y, z = blockIdx.z;
  const _Float16* Ain = z == 0 ? A0 : z == 1 ? A1 : A2;
  const _Float16* W   = z == 0 ? W0 : z == 1 ? W1 : W2;
  const float* bias   = z == 0 ? b0 : z == 1 ? b1 : b2;

  const int wid = tid >> 6, lane = tid & 63;
  const int wm = wid >> 2, wn = wid & 3;
  const int lr = lane & 15, lg = lane >> 4;

  f32x4 acc[4][2];
#pragma unroll
  for (int i = 0; i < 4; ++i)
#pragma unroll
    for (int j = 0; j < 2; ++j) acc[i][j] = (f32x4){0.f, 0.f, 0.f, 0.f};

  size_t aoff, woff;
  {
    const int o = wid * 1024 + lane * 16;
    const int prow = o >> 7, pb = o & 127;
    const int lb = pb ^ ((prow & 7) << 4);
    const int r = (prow << 1) | (lb >> 6), c = lb & 63;
    aoff = (size_t)(bm * 128 + r) * astride + c;
    woff = (size_t)(bn * 128 + r) * 4096 + c;
  }

  auto stage = [&](int kt, int buf) {
    gl_lds16((const char*)Ain + aoff + kt * 64, Abuf + buf * 8192 + wid * 1024);
    gl_lds16((const char*)W + woff + kt * 64, Wbuf + buf * 8192 + wid * 1024);
  };

  auto lds_addr = [](const char* base, int r, int cb) -> const char* {
    return base + ((r >> 1) << 7) + ((((r & 1) << 6) | cb) ^ (((r >> 1) & 7) << 4));
  };

  auto compute = [&](int buf) {
    const char* ab = Abuf + buf * 8192;
    const char* wb = Wbuf + buf * 8192;
    half8 af[4], bf[2];
#pragma unroll
    for (int i = 0; i < 4; ++i)
      af[i] = *(const half8*)lds_addr(ab, wm * 64 + i * 16 + lr, lg << 4);
#pragma unroll
    for (int j = 0; j < 2; ++j)
      bf[j] = *(const half8*)lds_addr(wb, wn * 32 + j * 16 + lr, lg << 4);
#pragma unroll
    for (int i = 0; i < 4; ++i)
#pragma unroll
      for (int j = 0; j < 2; ++j)
        acc[i][j] = __builtin_amdgcn_mfma_f32_16x16x32_f16(af[i], bf[j], acc[i][j], 0, 0, 0);
  };

  const int NKT = DM / 32;
  stage(0, 0);
  __syncthreads();
  for (int kt = 0; kt < NKT; ++kt) {
    if (kt + 1 < NKT) stage(kt + 1, (kt + 1) & 1);
    compute(kt & 1);
    __syncthreads();
  }

  const float qscale = 0.08838834764831845f * 1.4426950408889634f;
#pragma unroll
  for (int i = 0; i < 4; ++i) {
    const int m0 = bm * 128 + wm * 64 + i * 16 + lg * 4;
#pragma unroll
    for (int j = 0; j < 2; ++j) {
      const int gn = bn * 128 + wn * 32 + j * 16 + lr;
      const float bb = bias[gn];
      if constexpr (MODE == 1) {
#pragma unroll
        for (int r = 0; r < 4; ++r)
          Co[(size_t)(m0 + r) * DM + gn] = acc[i][j][r] + bb;
      } else {
        if (z == 0) {
#pragma unroll
          for (int r = 0; r < 4; ++r)
            Qp[(size_t)(m0 + r) * DM + gn] = (_Float16)((acc[i][j][r] + bb) * qscale);
        } else if (z == 1) {
          const int b = m0 >> 9;
#pragma unroll
          for (int r = 0; r < 4; ++r)
            Kc[((size_t)b * TT + CL + ((m0 + r) & 511)) * DM + gn] =
                (_Float16)(acc[i][j][r] + bb);
        } else {
          half4v hv;
#pragma unroll
          for (int r = 0; r < 4; ++r) hv[r] = (_Float16)(acc[i][j][r] + bb);
          const int b = m0 >> 9, t = CL + (m0 & 511);
          const int h = gn >> 7, d = gn & 127;
          *(half4v*)&Vt[((size_t)(b * NH + h) * DH + d) * TT + t] = hv;
        }
      }
    }
  }
}

// ---------------- flash attention v8: 4-wave blocks, 64KB LDS (2 blocks/CU), register-P ----------------
// 512 blocks (b,h,qb0..3,part), 256 threads = 4 waves x 32 q; KVB=64.
// LDS = K dbuf 32K + V dbuf 32K = 64KB. P stays in registers (cvt_pkrtz + shuffle regather, R6-proven).
__global__ __launch_bounds__(256) void attn_kernel(
    const _Float16* __restrict__ Qp, const _Float16* __restrict__ Kc,
    const _Float16* __restrict__ Vt, _Float16* __restrict__ O0,
    _Float16* __restrict__ O1, float2* __restrict__ ml)
{
  __shared__ _Float16 Ks[2][64 * 128];
  __shared__ _Float16 VTs[2][128 * 64];

  const int tid = threadIdx.x;
  const int lin = blockIdx.x;
  const int xcd = lin & 7, slot = lin >> 3;     // 512 blocks
  const int pair = xcd * 8 + (slot >> 3);       // (b,h) 0..63, 8 blocks/pair on one XCD
  const int rem = slot & 7;
  const int qb = rem >> 1, part = rem & 1;      // qb 0..3 (128 q each), kv-part 0/1
  const int b = pair >> 4, h = pair & 15;

  const int wid = tid >> 6, lane = tid & 63;
  const int lr = lane & 15, lg = lane >> 4;
  const int qw = qb * 128 + wid * 32;

  // Q fragments: [qsub][kk]
  half8 qf[2][4];
#pragma unroll
  for (int qs = 0; qs < 2; ++qs)
#pragma unroll
    for (int kk = 0; kk < 4; ++kk)
      qf[qs][kk] = *(const half8*)&Qp[(size_t)(b * SQ + qw + qs * 16 + lr) * DM +
                                      h * DH + kk * 32 + lg * 8];

  f32x4 zero = {0.f, 0.f, 0.f, 0.f};
  f32x4 acc[8][2];  // [dblk][qsub]: O^T, d = dblk*16+lg*4+r, q = qsub*16+lr
#pragma unroll
  for (int d = 0; d < 8; ++d)
#pragma unroll
    for (int qs = 0; qs < 2; ++qs) acc[d][qs] = zero;
  float m_run[2] = {-1e30f, -1e30f}, l_run[2] = {0.f, 0.f};

  const int nt_full = (CL + qb * 128 + 128) / 64;  // 58,60,62,64
  const int halfn = nt_full >> 1;
  const int tbeg = part ? halfn : 0;
  const int nt = part ? (nt_full - halfn) : halfn;

  // pre-unswizzled global source offsets; 1024 granules per tile, p = c*256 + tid
  int ksrc[4], vsrc[4];
#pragma unroll
  for (int c = 0; c < 4; ++c) {
    const int p = c * 256 + tid;
    { const int r = p >> 4, pg = p & 15, gc = pg ^ (r & 7);
      ksrc[c] = r * DM + gc * 8; }
    { const int d = p >> 3, pg = p & 7, gt = pg ^ (d & 7);
      vsrc[c] = d * TT + gt * 8; }
  }
  const _Float16* Kb = Kc + (size_t)b * TT * DM + h * DH;
  const _Float16* Vb = Vt + (size_t)(b * NH + h) * DH * TT;

  auto stage = [&](int tt, int buf) {
    const int t0 = (tbeg + tt) * 64;
#pragma unroll
    for (int c = 0; c < 4; ++c)
      gl_lds16(Kb + (size_t)t0 * DM + ksrc[c], &Ks[buf][(c * 256 + tid) * 8]);
#pragma unroll
    for (int c = 0; c < 4; ++c)
      gl_lds16(Vb + t0 + vsrc[c], &VTs[buf][(c * 256 + tid) * 8]);
  };

  f32x4 s[4][2];
  int w0q[2][4], w1q[2][4];   // packed f16 P pairs per qsub

  // shuffle sources for P regather (R6-proven mapping)
  const int srcA = ((lg & 1) * 2) * 16 + lr;
  const int srcB = srcA + 16;
  const bool sel = (lg >> 1) != 0;

  stage(0, 0);
  __syncthreads();

  for (int t = 0; t < nt; ++t) {
    const int cur = t & 1;
    if (t + 1 < nt) stage(t + 1, cur ^ 1);

    // S^T = K Q^T (same tile)
#pragma unroll
    for (int j = 0; j < 4; ++j)
#pragma unroll
      for (int qs = 0; qs < 2; ++qs) s[j][qs] = zero;
    __builtin_amdgcn_s_setprio(1);
#pragma unroll
    for (int kk = 0; kk < 4; ++kk)
#pragma unroll
      for (int j = 0; j < 4; ++j) {
        half8 kb = *(const half8*)&Ks[cur][KSW(j * 16 + lr, kk * 32 + lg * 8)];
        s[j][0] = __builtin_amdgcn_mfma_f32_16x16x32_f16(kb, qf[0][kk], s[j][0], 0, 0, 0);
        s[j][1] = __builtin_amdgcn_mfma_f32_16x16x32_f16(kb, qf[1][kk], s[j][1], 0, 0, 0);
      }
    __builtin_amdgcn_s_setprio(0);

    // causal mask: only part-1 tail tiles can mask
    if (part) {
      const int t0 = (tbeg + t) * 64;
      if (t0 + 63 > CL + qw) {
#pragma unroll
        for (int j = 0; j < 4; ++j)
#pragma unroll
          for (int qs = 0; qs < 2; ++qs)
#pragma unroll
            for (int r = 0; r < 4; ++r)
              if (t0 + j * 16 + lg * 4 + r > CL + qw + qs * 16 + lr) s[j][qs][r] = -1e30f;
      }
    }

    // online softmax, defer-max, per-lane partial l
    float mt[2];
#pragma unroll
    for (int qs = 0; qs < 2; ++qs) {
      float m = s[0][qs][0];
#pragma unroll
      for (int j = 0; j < 4; ++j)
#pragma unroll
        for (int r = 0; r < 4; ++r) m = fmaxf(m, s[j][qs][r]);
      mt[qs] = m;
    }
    if (!__all(mt[0] <= m_run[0] + 10.0f && mt[1] <= m_run[1] + 10.0f)) {
#pragma unroll
      for (int qs = 0; qs < 2; ++qs) {
        float m = fmaxf(mt[qs], __shfl_xor(mt[qs], 16));
        m = fmaxf(m, __shfl_xor(m, 32));
        const float mn = fmaxf(m_run[qs], m);
        const float fsc = exp2f(m_run[qs] - mn);
        m_run[qs] = mn;
        l_run[qs] *= fsc;
#pragma unroll
        for (int d = 0; d < 8; ++d)
#pragma unroll
          for (int r = 0; r < 4; ++r) acc[d][qs][r] *= fsc;
      }
    }
#pragma unroll
    for (int qs = 0; qs < 2; ++qs) {
      float ps = 0.f;
#pragma unroll
      for (int j = 0; j < 4; ++j) {
        float p0 = exp2f(s[j][qs][0] - m_run[qs]);
        float p1 = exp2f(s[j][qs][1] - m_run[qs]);
        float p2 = exp2f(s[j][qs][2] - m_run[qs]);
        float p3 = exp2f(s[j][qs][3] - m_run[qs]);
        ps += (p0 + p1) + (p2 + p3);
        w0q[qs][j] = __builtin_bit_cast(int, __builtin_amdgcn_cvt_pkrtz(p0, p1));
        w1q[qs][j] = __builtin_bit_cast(int, __builtin_amdgcn_cvt_pkrtz(p2, p3));
      }
      l_run[qs] += ps;
    }

    // regather P into B-operand fragments via shuffles; O^T += V^T P^T
#pragma unroll
    for (int kk = 0; kk < 2; ++kk) {
      half8 pf[2];
#pragma unroll
      for (int qs = 0; qs < 2; ++qs) {
        const int a00 = __shfl(w0q[qs][2 * kk], srcA), a01 = __shfl(w1q[qs][2 * kk], srcA);
        const int a10 = __shfl(w0q[qs][2 * kk + 1], srcA), a11 = __shfl(w1q[qs][2 * kk + 1], srcA);
        const int b00 = __shfl(w0q[qs][2 * kk], srcB), b01 = __shfl(w1q[qs][2 * kk], srcB);
        const int b10 = __shfl(w0q[qs][2 * kk + 1], srcB), b11 = __shfl(w1q[qs][2 * kk + 1], srcB);
        uint4 u;
        u.x = sel ? a10 : a00;
        u.y = sel ? a11 : a01;
        u.z = sel ? b10 : b00;
        u.w = sel ? b11 : b01;
        pf[qs] = __builtin_bit_cast(half8, u);
      }
      __builtin_amdgcn_s_setprio(1);
#pragma unroll
      for (int d = 0; d < 8; ++d) {
        half8 vf = *(const half8*)&VTs[cur][VSW(d * 16 + lr, kk * 32 + lg * 8)];
        acc[d][0] = __builtin_amdgcn_mfma_f32_16x16x32_f16(vf, pf[0], acc[d][0], 0, 0, 0);
        acc[d][1] = __builtin_amdgcn_mfma_f32_16x16x32_f16(vf, pf[1], acc[d][1], 0, 0, 0);
      }
      __builtin_amdgcn_s_setprio(0);
    }

    __syncthreads();
  }

  _Float16* Od = part ? O1 : O0;
#pragma unroll
  for (int qs = 0; qs < 2; ++qs) {
    float lt = l_run[qs] + __shfl_xor(l_run[qs], 16);
    lt += __shfl_xor(lt, 32);
    const float inv = 1.0f / lt;
#pragma unroll
    for (int d = 0; d < 8; ++d) {
      half4v hv;
#pragma unroll
      for (int r = 0; r < 4; ++r) hv[r] = (_Float16)(acc[d][qs][r] * inv);
      *(half4v*)&Od[(size_t)(b * SQ + qw + qs * 16 + lr) * DM + h * DH + d * 16 + lg * 4] = hv;
    }
    if (lg == 0) {
      float2 e; e.x = m_run[qs]; e.y = lt;
      ml[part * (64 * SQ) + ((b * NH + h) * SQ) + qw + qs * 16 + lr] = e;
    }
  }
}

// ---------------- combine the two kv-partitions ----------------
__global__ __launch_bounds__(256) void combine(
    _Float16* __restrict__ AO, const _Float16* __restrict__ O1,
    const float2* __restrict__ ml)
{
  const int idx = blockIdx.x * 256 + threadIdx.x;
  const int row = idx >> 8;
  const int col0 = (idx & 255) * 8;
  const int b = row >> 9, q = row & 511, h = col0 >> 7;
  const float2 e0 = ml[(b * NH + h) * SQ + q];
  const float2 e1 = ml[64 * SQ + (b * NH + h) * SQ + q];
  const float m = fmaxf(e0.x, e1.x);
  float w0 = e0.y * exp2f(e0.x - m);
  float w1 = e1.y * exp2f(e1.x - m);
  const float inv = 1.0f / (w0 + w1);
  w0 *= inv; w1 *= inv;
  const size_t o = (size_t)row * DM + col0;
  half8 a = *(const half8*)&AO[o];
  half8 c = *(const half8*)&O1[o];
  half8 r;
#pragma unroll
  for (int i = 0; i < 8; ++i)
    r[i] = (_Float16)(w0 * (float)a[i] + w1 * (float)c[i]);
  *(half8*)&AO[o] = r;
}

extern "C" void kernel_launch(void* const* d_in, const int* in_sizes, int n_in,
                              void* d_out, int out_size, void* d_ws, size_t ws_size,
                              hipStream_t stream) {
  const float* query = (const float*)d_in[0];
  const float* key   = (const float*)d_in[1];
  const float* value = (const float*)d_in[2];
  const float* ck    = (const float*)d_in[3];
  const float* cv    = (const float*)d_in[4];
  const float* wq = (const float*)d_in[5];
  const float* bq = (const float*)d_in[6];
  const float* wk = (const float*)d_in[7];
  const float* bk = (const float*)d_in[8];
  const float* wv = (const float*)d_in[9];
  const float* bv = (const float*)d_in[10];
  const float* wo = (const float*)d_in[11];
  const float* bo = (const float*)d_in[12];

  char* ws = (char*)d_ws;
  _Float16* Kc = (_Float16*)ws;                 // 64 MiB
  _Float16* Vt = (_Float16*)(ws + 67108864);    // 64 MiB
  _Float16* Qp = (_Float16*)(ws + 134217728);   // 8 MiB
  _Float16* AO = (_Float16*)(ws + 142606336);   // 8 MiB

  // d_out (16 MiB fp32) as pre-o_gemm scratch: partition-1 partial + m/l
  _Float16* O1s = (_Float16*)d_out;                // 8 MiB
  float2* mls = (float2*)((char*)d_out + 8388608); // 512 KiB

  _Float16* wqh = Kc;
  _Float16* wkh = Kc + 8388608;
  _Float16* wvh = Kc + 16777216;
  _Float16* qh = Vt;
  _Float16* kh = Vt + 2048 * 4096;
  _Float16* vh = Vt + 4096 * 4096;
  _Float16* woh = Qp;

  cvt_f16<<<dim3(512, 3), 256, 0, stream>>>(query, key, value, qh, kh, vh, 4096);
  cvt_f16<<<dim3(512, 3), 256, 0, stream>>>(wq, wk, wv, wqh, wkh, wvh, 2048);
  mm16<0><<<dim3(16, 16, 3), 512, 0, stream>>>(
      qh, kh, vh, 8192, wqh, wkh, wvh, bq, bk, bv, Qp, Kc, Vt, nullptr);
  convert_K<<<2048, 256, 0, stream>>>(ck, Kc);
  transpose_V<<<dim3(CL / 64, DM / 64, NB), 256, 0, stream>>>(cv, Vt);
  attn_kernel<<<512, 256, 0, stream>>>(Qp, Kc, Vt, AO, O1s, mls);
  combine<<<2048, 256, 0, stream>>>(AO, O1s, mls);
  cvt_f16<<<dim3(512, 1), 256, 0, stream>>>(wo, wo, wo, woh, woh, woh, 2048);
  mm16<1><<<dim3(16, 16, 1), 512, 0, stream>>>(
      AO, AO, AO, 4096, woh, woh, woh, bo, bo, bo, nullptr, nullptr, nullptr,
      (float*)d_out);
}

// Round 11
// 322.970 us; speedup vs baseline: 1.2353x; 1.2353x over previous
//
#include <hip/hip_runtime.h>

typedef _Float16 half8 __attribute__((ext_vector_type(8)));
typedef _Float16 half4v __attribute__((ext_vector_type(4)));
typedef float f32x4 __attribute__((ext_vector_type(4)));

#define NB 4
#define SQ 512
#define CL 3584
#define TT 4096
#define DM 2048
#define NH 16
#define DH 128

// XOR swizzles on half-index (attn LDS)
#define KSW(row, col) ((((row) * 128) + (col)) ^ ((((row) & 7) << 3)))
#define VSW(row, col) ((((row) * 64) + (col)) ^ ((((row) & 7) << 3)))
#define PSW(row, col) ((((row) * 64) + (col)) ^ ((((row) & 7) << 3)))

__device__ __forceinline__ void gl_lds16(const void* g, void* l) {
  __builtin_amdgcn_global_load_lds(
      (const __attribute__((address_space(1))) unsigned int*)g,
      (__attribute__((address_space(3))) unsigned int*)l, 16, 0, 0);
}

// ---------------- fp32 -> f16 convert, 6 slices in one launch ----------------
// z 0..2: inputs q/k/v -> strided dst (4096); z 3..5: weights -> dense (2048)
__global__ __launch_bounds__(256) void cvt_f16(
    const float* __restrict__ s0, const float* __restrict__ s1, const float* __restrict__ s2,
    const float* __restrict__ s3, const float* __restrict__ s4, const float* __restrict__ s5,
    _Float16* __restrict__ d0, _Float16* __restrict__ d1, _Float16* __restrict__ d2,
    _Float16* __restrict__ d3, _Float16* __restrict__ d4, _Float16* __restrict__ d5)
{
  const int z = blockIdx.y;
  const float* s = z == 0 ? s0 : z == 1 ? s1 : z == 2 ? s2 : z == 3 ? s3 : z == 4 ? s4 : s5;
  _Float16* d = z == 0 ? d0 : z == 1 ? d1 : z == 2 ? d2 : z == 3 ? d3 : z == 4 ? d4 : d5;
  const int dstride = z < 3 ? 4096 : 2048;
  const int n4 = DM * DM / 4;
  for (int v = blockIdx.x * blockDim.x + threadIdx.x; v < n4;
       v += gridDim.x * blockDim.x) {
    float4 x = ((const float4*)s)[v];
    half4v h = { (_Float16)x.x, (_Float16)x.y, (_Float16)x.z, (_Float16)x.w };
    const int m = v >> 9, c = (v << 2) & 2047;
    *(half4v*)&d[(size_t)m * dstride + c] = h;
  }
}

// single-matrix variant for wo (runs after attn; Qp region becomes free)
__global__ __launch_bounds__(256) void cvt_f16_one(
    const float* __restrict__ s, _Float16* __restrict__ d)
{
  const int n4 = DM * DM / 4;
  for (int v = blockIdx.x * blockDim.x + threadIdx.x; v < n4;
       v += gridDim.x * blockDim.x) {
    float4 x = ((const float4*)s)[v];
    half4v h = { (_Float16)x.x, (_Float16)x.y, (_Float16)x.z, (_Float16)x.w };
    ((half4v*)d)[v] = h;
  }
}

// ---------------- cached K fp32 -> f16 linear convert ----------------
__global__ __launch_bounds__(256) void convert_K(
    const float* __restrict__ ck, _Float16* __restrict__ K)
{
  const long long nvec = (long long)NB * CL * DM / 4;
  const int pb = CL * DM / 4;
  for (long long v = (long long)blockIdx.x * blockDim.x + threadIdx.x; v < nvec;
       v += (long long)gridDim.x * blockDim.x) {
    int b = (int)(v / pb);
    long long r = v - (long long)b * pb;
    float4 x = ((const float4*)ck)[v];
    half4v hx = { (_Float16)x.x, (_Float16)x.y, (_Float16)x.z, (_Float16)x.w };
    ((half4v*)K)[(long long)b * (TT * DM / 4) + r] = hx;
  }
}

// ---------------- cached V fp32 -> f16 transpose: Vt[b][h][d][t] ----------------
__global__ __launch_bounds__(256) void transpose_V(
    const float* __restrict__ cv, _Float16* __restrict__ Vt)
{
  __shared__ _Float16 T[64][72];
  const int t0 = blockIdx.x * 64;
  const int dm0 = blockIdx.y * 64;
  const int b = blockIdx.z;
  const int tid = threadIdx.x;
  {
    const int tr = tid >> 2, c0 = (tid & 3) * 16;
    const float* src = cv + ((size_t)b * CL + t0 + tr) * DM + dm0 + c0;
    float4 a0 = ((const float4*)src)[0];
    float4 a1 = ((const float4*)src)[1];
    float4 a2 = ((const float4*)src)[2];
    float4 a3 = ((const float4*)src)[3];
    half8 h0 = { (_Float16)a0.x, (_Float16)a0.y, (_Float16)a0.z, (_Float16)a0.w,
                 (_Float16)a1.x, (_Float16)a1.y, (_Float16)a1.z, (_Float16)a1.w };
    half8 h1 = { (_Float16)a2.x, (_Float16)a2.y, (_Float16)a2.z, (_Float16)a2.w,
                 (_Float16)a3.x, (_Float16)a3.y, (_Float16)a3.z, (_Float16)a3.w };
    *(half8*)&T[tr][c0] = h0;
    *(half8*)&T[tr][c0 + 8] = h1;
  }
  __syncthreads();
  {
    const int dl = tid >> 2, tc = (tid & 3) * 16;
    const int h = dm0 >> 7, d = (dm0 & 127) + dl;
    half8 o0, o1;
#pragma unroll
    for (int i = 0; i < 8; ++i) o0[i] = T[tc + i][dl];
#pragma unroll
    for (int i = 0; i < 8; ++i) o1[i] = T[tc + 8 + i][dl];
    _Float16* dst = Vt + ((size_t)(b * NH + h) * DH + d) * TT + t0 + tc;
    *(half8*)dst = o0;
    *(half8*)(dst + 8) = o1;
  }
}

// ---------------- f16 GEMM via global_load_lds (unchanged from R4) ----------------
template<int MODE>
__global__ __launch_bounds__(512, 4) void mm16(
    const _Float16* __restrict__ A0, const _Float16* __restrict__ A1,
    const _Float16* __restrict__ A2, int astride,
    const _Float16* __restrict__ W0, const _Float16* __restrict__ W1,
    const _Float16* __restrict__ W2,
    const float* __restrict__ b0, const float* __restrict__ b1,
    const float* __restrict__ b2,
    _Float16* __restrict__ Qp, _Float16* __restrict__ Kc,
    _Float16* __restrict__ Vt, float* __restrict__ Co)
{
  __shared__ __align__(16) char smem[4 * 8192];
  char* Abuf = smem;
  char* Wbuf = smem + 2 * 8192;

  const int tid = threadIdx.x;
  const int bm = blockIdx.x, bn = blockIdx.y, z = blockIdx.z;
  const _Float16* Ain = z == 0 ? A0 : z == 1 ? A1 : A2;
  const _Float16* W   = z == 0 ? W0 : z == 1 ? W1 : W2;
  const float* bias   = z == 0 ? b0 : z == 1 ? b1 : b2;

  const int wid = tid >> 6, lane = tid & 63;
  const int wm = wid >> 2, wn = wid & 3;
  const int lr = lane & 15, lg = lane >> 4;

  f32x4 acc[4][2];
#pragma unroll
  for (int i = 0; i < 4; ++i)
#pragma unroll
    for (int j = 0; j < 2; ++j) acc[i][j] = (f32x4){0.f, 0.f, 0.f, 0.f};

  size_t aoff, woff;
  {
    const int o = wid * 1024 + lane * 16;
    const int prow = o >> 7, pb = o & 127;
    const int lb = pb ^ ((prow & 7) << 4);
    const int r = (prow << 1) | (lb >> 6), c = lb & 63;
    aoff = (size_t)(bm * 128 + r) * astride + c;
    woff = (size_t)(bn * 128 + r) * 4096 + c;
  }

  auto stage = [&](int kt, int buf) {
    gl_lds16((const char*)Ain + aoff + kt * 64, Abuf + buf * 8192 + wid * 1024);
    gl_lds16((const char*)W + woff + kt * 64, Wbuf + buf * 8192 + wid * 1024);
  };

  auto lds_addr = [](const char* base, int r, int cb) -> const char* {
    return base + ((r >> 1) << 7) + ((((r & 1) << 6) | cb) ^ (((r >> 1) & 7) << 4));
  };

  auto compute = [&](int buf) {
    const char* ab = Abuf + buf * 8192;
    const char* wb = Wbuf + buf * 8192;
    half8 af[4], bf[2];
#pragma unroll
    for (int i = 0; i < 4; ++i)
      af[i] = *(const half8*)lds_addr(ab, wm * 64 + i * 16 + lr, lg << 4);
#pragma unroll
    for (int j = 0; j < 2; ++j)
      bf[j] = *(const half8*)lds_addr(wb, wn * 32 + j * 16 + lr, lg << 4);
#pragma unroll
    for (int i = 0; i < 4; ++i)
#pragma unroll
      for (int j = 0; j < 2; ++j)
        acc[i][j] = __builtin_amdgcn_mfma_f32_16x16x32_f16(af[i], bf[j], acc[i][j], 0, 0, 0);
  };

  const int NKT = DM / 32;
  stage(0, 0);
  __syncthreads();
  for (int kt = 0; kt < NKT; ++kt) {
    if (kt + 1 < NKT) stage(kt + 1, (kt + 1) & 1);
    compute(kt & 1);
    __syncthreads();
  }

  const float qscale = 0.08838834764831845f * 1.4426950408889634f;
#pragma unroll
  for (int i = 0; i < 4; ++i) {
    const int m0 = bm * 128 + wm * 64 + i * 16 + lg * 4;
#pragma unroll
    for (int j = 0; j < 2; ++j) {
      const int gn = bn * 128 + wn * 32 + j * 16 + lr;
      const float bb = bias[gn];
      if constexpr (MODE == 1) {
#pragma unroll
        for (int r = 0; r < 4; ++r)
          Co[(size_t)(m0 + r) * DM + gn] = acc[i][j][r] + bb;
      } else {
        if (z == 0) {
#pragma unroll
          for (int r = 0; r < 4; ++r)
            Qp[(size_t)(m0 + r) * DM + gn] = (_Float16)((acc[i][j][r] + bb) * qscale);
        } else if (z == 1) {
          const int b = m0 >> 9;
#pragma unroll
          for (int r = 0; r < 4; ++r)
            Kc[((size_t)b * TT + CL + ((m0 + r) & 511)) * DM + gn] =
                (_Float16)(acc[i][j][r] + bb);
        } else {
          half4v hv;
#pragma unroll
          for (int r = 0; r < 4; ++r) hv[r] = (_Float16)(acc[i][j][r] + bb);
          const int b = m0 >> 9, t = CL + (m0 & 511);
          const int h = gn >> 7, d = gn & 127;
          *(half4v*)&Vt[((size_t)(b * NH + h) * DH + d) * TT + t] = hv;
        }
      }
    }
  }
}

// ---------------- flash attention (R8 structure + setprio + gated mask) ----------------
// 256 blocks, 512 threads = 8 waves x 32 q rows = 256 q/block; KVB=64; kv-split x2.
// K dbuf (32KB) + V tribuf (48KB) + P (32KB) = 112KB LDS, 1 block/CU.
// Pipelined: iter t does qk(t) [MFMA] || softmax(t-1)+pv(t-1).
__global__ __launch_bounds__(512) void attn_kernel(
    const _Float16* __restrict__ Qp, const _Float16* __restrict__ Kc,
    const _Float16* __restrict__ Vt, _Float16* __restrict__ O0,
    _Float16* __restrict__ O1, float2* __restrict__ ml)
{
  __shared__ _Float16 Ks[2][64 * 128];
  __shared__ _Float16 VTs[3][128 * 64];
  __shared__ _Float16 Ps[8][32 * 64];

  const int tid = threadIdx.x;
  const int lin = blockIdx.x;
  const int xcd = lin & 7, slot = lin >> 3;
  const int pair = xcd * 8 + (slot >> 2);
  const int rem = slot & 3;
  const int qb = rem >> 1, part = rem & 1;
  const int b = pair >> 4, h = pair & 15;

  const int wid = tid >> 6, lane = tid & 63;
  const int lr = lane & 15, lg = lane >> 4;
  const int qw = qb * 256 + wid * 32;

  // Q fragments: [qsub][kk]
  half8 qf[2][4];
#pragma unroll
  for (int qs = 0; qs < 2; ++qs)
#pragma unroll
    for (int kk = 0; kk < 4; ++kk)
      qf[qs][kk] = *(const half8*)&Qp[(size_t)(b * SQ + qw + qs * 16 + lr) * DM +
                                      h * DH + kk * 32 + lg * 8];

  f32x4 zero = {0.f, 0.f, 0.f, 0.f};
  f32x4 acc[8][2];  // [dblk][qsub]: O^T, d = dblk*16+lg*4+r, q = qsub*16+lr
#pragma unroll
  for (int d = 0; d < 8; ++d)
#pragma unroll
    for (int qs = 0; qs < 2; ++qs) acc[d][qs] = zero;
  float m_run[2] = {-1e30f, -1e30f}, l_run[2] = {0.f, 0.f};

  const int nt_full = (CL + qb * 256 + 256) / 64;  // 60 or 64
  const int halfn = nt_full >> 1;
  const int tbeg = part ? halfn : 0;
  const int nt = part ? (nt_full - halfn) : halfn;

  // pre-unswizzled global source offsets; p = c*512 + wid*64 + lane (1024 granules)
  int ksrc[2], vsrc[2];
#pragma unroll
  for (int c = 0; c < 2; ++c) {
    const int p = c * 512 + wid * 64 + lane;
    { const int r = p >> 4, pg = p & 15, gc = pg ^ (r & 7);
      ksrc[c] = r * DM + gc * 8; }
    { const int d = p >> 3, pg = p & 7, gt = pg ^ (d & 7);
      vsrc[c] = d * TT + gt * 8; }
  }
  const _Float16* Kb = Kc + (size_t)b * TT * DM + h * DH;
  const _Float16* Vb = Vt + (size_t)(b * NH + h) * DH * TT;

  auto stage = [&](int tt, int kbuf, int vbuf) {
    const int t0 = (tbeg + tt) * 64;
#pragma unroll
    for (int c = 0; c < 2; ++c)
      gl_lds16(Kb + (size_t)t0 * DM + ksrc[c], &Ks[kbuf][(c * 512 + wid * 64) * 8]);
#pragma unroll
    for (int c = 0; c < 2; ++c)
      gl_lds16(Vb + t0 + vsrc[c], &VTs[vbuf][(c * 512 + wid * 64) * 8]);
  };

  auto qk = [&](int kbuf, f32x4 (*s)[2]) {
#pragma unroll
    for (int j = 0; j < 4; ++j)
#pragma unroll
      for (int qs = 0; qs < 2; ++qs) s[j][qs] = zero;
    __builtin_amdgcn_s_setprio(1);
#pragma unroll
    for (int kk = 0; kk < 4; ++kk)
#pragma unroll
      for (int j = 0; j < 4; ++j) {
        half8 kb = *(const half8*)&Ks[kbuf][KSW(j * 16 + lr, kk * 32 + lg * 8)];
        s[j][0] = __builtin_amdgcn_mfma_f32_16x16x32_f16(kb, qf[0][kk], s[j][0], 0, 0, 0);
        s[j][1] = __builtin_amdgcn_mfma_f32_16x16x32_f16(kb, qf[1][kk], s[j][1], 0, 0, 0);
      }
    __builtin_amdgcn_s_setprio(0);
  };

  auto mask_s = [&](int t0, f32x4 (*s)[2]) {
    if (part && t0 + 63 > CL + qw) {
#pragma unroll
      for (int j = 0; j < 4; ++j)
#pragma unroll
        for (int qs = 0; qs < 2; ++qs)
#pragma unroll
          for (int r = 0; r < 4; ++r)
            if (t0 + j * 16 + lg * 4 + r > CL + qw + qs * 16 + lr) s[j][qs][r] = -1e30f;
    }
  };

  auto softmax_step = [&](f32x4 (*s)[2]) {
    float mt[2];
#pragma unroll
    for (int qs = 0; qs < 2; ++qs) {
      float m = s[0][qs][0];
#pragma unroll
      for (int j = 0; j < 4; ++j)
#pragma unroll
        for (int r = 0; r < 4; ++r) m = fmaxf(m, s[j][qs][r]);
      mt[qs] = m;
    }
    if (!__all(mt[0] <= m_run[0] + 10.0f && mt[1] <= m_run[1] + 10.0f)) {
#pragma unroll
      for (int qs = 0; qs < 2; ++qs) {
        float m = fmaxf(mt[qs], __shfl_xor(mt[qs], 16));
        m = fmaxf(m, __shfl_xor(m, 32));
        const float mn = fmaxf(m_run[qs], m);
        const float fsc = exp2f(m_run[qs] - mn);
        m_run[qs] = mn;
        l_run[qs] *= fsc;
#pragma unroll
        for (int d = 0; d < 8; ++d)
#pragma unroll
          for (int r = 0; r < 4; ++r) acc[d][qs][r] *= fsc;
      }
    }
#pragma unroll
    for (int qs = 0; qs < 2; ++qs) {
      float ps = 0.f;
#pragma unroll
      for (int j = 0; j < 4; ++j) {
        float p0 = exp2f(s[j][qs][0] - m_run[qs]);
        float p1 = exp2f(s[j][qs][1] - m_run[qs]);
        float p2 = exp2f(s[j][qs][2] - m_run[qs]);
        float p3 = exp2f(s[j][qs][3] - m_run[qs]);
        ps += (p0 + p1) + (p2 + p3);
        half4v hp = { (_Float16)p0, (_Float16)p1, (_Float16)p2, (_Float16)p3 };
        *(half4v*)&Ps[wid][PSW(qs * 16 + lr, j * 16 + lg * 4)] = hp;
      }
      l_run[qs] += ps;
    }
  };

  auto pv = [&](int vbuf) {
    __builtin_amdgcn_s_setprio(1);
#pragma unroll
    for (int kk = 0; kk < 2; ++kk) {
      half8 pf0 = *(const half8*)&Ps[wid][PSW(lr, kk * 32 + lg * 8)];
      half8 pf1 = *(const half8*)&Ps[wid][PSW(16 + lr, kk * 32 + lg * 8)];
#pragma unroll
      for (int d = 0; d < 8; ++d) {
        half8 vf = *(const half8*)&VTs[vbuf][VSW(d * 16 + lr, kk * 32 + lg * 8)];
        acc[d][0] = __builtin_amdgcn_mfma_f32_16x16x32_f16(vf, pf0, acc[d][0], 0, 0, 0);
        acc[d][1] = __builtin_amdgcn_mfma_f32_16x16x32_f16(vf, pf1, acc[d][1], 0, 0, 0);
      }
    }
    __builtin_amdgcn_s_setprio(0);
  };

  f32x4 sp[4][2], sc[4][2];

  stage(0, 0, 0);
  __syncthreads();
  stage(1, 1, 1);
  qk(0, sp);
  mask_s(tbeg * 64, sp);

  for (int t = 1; t < nt; ++t) {
    __syncthreads();
    if (t + 1 < nt) stage(t + 1, (t + 1) & 1, (t + 1) % 3);
    qk(t & 1, sc);
    softmax_step(sp);
    pv((t - 1) % 3);
    mask_s((tbeg + t) * 64, sc);
#pragma unroll
    for (int j = 0; j < 4; ++j)
#pragma unroll
      for (int qs = 0; qs < 2; ++qs) sp[j][qs] = sc[j][qs];
  }
  softmax_step(sp);
  pv((nt - 1) % 3);

  _Float16* Od = part ? O1 : O0;
#pragma unroll
  for (int qs = 0; qs < 2; ++qs) {
    float lt = l_run[qs] + __shfl_xor(l_run[qs], 16);
    lt += __shfl_xor(lt, 32);
    const float inv = 1.0f / lt;
#pragma unroll
    for (int d = 0; d < 8; ++d) {
      half4v hv;
#pragma unroll
      for (int r = 0; r < 4; ++r) hv[r] = (_Float16)(acc[d][qs][r] * inv);
      *(half4v*)&Od[(size_t)(b * SQ + qw + qs * 16 + lr) * DM + h * DH + d * 16 + lg * 4] = hv;
    }
    if (lg == 0) {
      float2 e; e.x = m_run[qs]; e.y = lt;
      ml[part * (64 * SQ) + ((b * NH + h) * SQ) + qw + qs * 16 + lr] = e;
    }
  }
}

// ---------------- combine the two kv-partitions ----------------
__global__ __launch_bounds__(256) void combine(
    _Float16* __restrict__ AO, const _Float16* __restrict__ O1,
    const float2* __restrict__ ml)
{
  const int idx = blockIdx.x * 256 + threadIdx.x;
  const int row = idx >> 8;
  const int col0 = (idx & 255) * 8;
  const int b = row >> 9, q = row & 511, h = col0 >> 7;
  const float2 e0 = ml[(b * NH + h) * SQ + q];
  const float2 e1 = ml[64 * SQ + (b * NH + h) * SQ + q];
  const float m = fmaxf(e0.x, e1.x);
  float w0 = e0.y * exp2f(e0.x - m);
  float w1 = e1.y * exp2f(e1.x - m);
  const float inv = 1.0f / (w0 + w1);
  w0 *= inv; w1 *= inv;
  const size_t o = (size_t)row * DM + col0;
  half8 a = *(const half8*)&AO[o];
  half8 c = *(const half8*)&O1[o];
  half8 r;
#pragma unroll
  for (int i = 0; i < 8; ++i)
    r[i] = (_Float16)(w0 * (float)a[i] + w1 * (float)c[i]);
  *(half8*)&AO[o] = r;
}

extern "C" void kernel_launch(void* const* d_in, const int* in_sizes, int n_in,
                              void* d_out, int out_size, void* d_ws, size_t ws_size,
                              hipStream_t stream) {
  const float* query = (const float*)d_in[0];
  const float* key   = (const float*)d_in[1];
  const float* value = (const float*)d_in[2];
  const float* ck    = (const float*)d_in[3];
  const float* cv    = (const float*)d_in[4];
  const float* wq = (const float*)d_in[5];
  const float* bq = (const float*)d_in[6];
  const float* wk = (const float*)d_in[7];
  const float* bk = (const float*)d_in[8];
  const float* wv = (const float*)d_in[9];
  const float* bv = (const float*)d_in[10];
  const float* wo = (const float*)d_in[11];
  const float* bo = (const float*)d_in[12];

  char* ws = (char*)d_ws;
  _Float16* Kc = (_Float16*)ws;                 // 64 MiB
  _Float16* Vt = (_Float16*)(ws + 67108864);    // 64 MiB
  _Float16* Qp = (_Float16*)(ws + 134217728);   // 8 MiB
  _Float16* AO = (_Float16*)(ws + 142606336);   // 8 MiB

  // d_out (16 MiB fp32) as pre-o_gemm scratch: partition-1 partial + m/l
  _Float16* O1s = (_Float16*)d_out;                // 8 MiB
  float2* mls = (float2*)((char*)d_out + 8388608); // 512 KiB

  _Float16* wqh = Kc;
  _Float16* wkh = Kc + 8388608;
  _Float16* wvh = Kc + 16777216;
  _Float16* qh = Vt;
  _Float16* kh = Vt + 2048 * 4096;
  _Float16* vh = Vt + 4096 * 4096;
  _Float16* woh = Qp;

  cvt_f16<<<dim3(512, 6), 256, 0, stream>>>(
      query, key, value, wq, wk, wv, qh, kh, vh, wqh, wkh, wvh);
  mm16<0><<<dim3(16, 16, 3), 512, 0, stream>>>(
      qh, kh, vh, 8192, wqh, wkh, wvh, bq, bk, bv, Qp, Kc, Vt, nullptr);
  convert_K<<<2048, 256, 0, stream>>>(ck, Kc);
  transpose_V<<<dim3(CL / 64, DM / 64, NB), 256, 0, stream>>>(cv, Vt);
  attn_kernel<<<256, 512, 0, stream>>>(Qp, Kc, Vt, AO, O1s, mls);
  combine<<<2048, 256, 0, stream>>>(AO, O1s, mls);
  cvt_f16_one<<<512, 256, 0, stream>>>(wo, woh);
  mm16<1><<<dim3(16, 16, 1), 512, 0, stream>>>(
      AO, AO, AO, 4096, woh, woh, woh, bo, bo, bo, nullptr, nullptr, nullptr,
      (float*)d_out);
}

// Round 12
// 315.709 us; speedup vs baseline: 1.2637x; 1.0230x over previous
//
#include <hip/hip_runtime.h>

typedef _Float16 half8 __attribute__((ext_vector_type(8)));
typedef _Float16 half4v __attribute__((ext_vector_type(4)));
typedef float f32x4 __attribute__((ext_vector_type(4)));

#define NB 4
#define SQ 512
#define CL 3584
#define TT 4096
#define DM 2048
#define NH 16
#define DH 128

// XOR swizzles on half-index (attn LDS)
#define KSW(row, col) ((((row) * 128) + (col)) ^ ((((row) & 7) << 3)))
#define VSW(row, col) ((((row) * 64) + (col)) ^ ((((row) & 7) << 3)))
#define PSW(row, col) ((((row) * 64) + (col)) ^ ((((row) & 7) << 3)))

__device__ __forceinline__ void gl_lds16(const void* g, void* l) {
  __builtin_amdgcn_global_load_lds(
      (const __attribute__((address_space(1))) unsigned int*)g,
      (__attribute__((address_space(3))) unsigned int*)l, 16, 0, 0);
}

// ---------------- fp32 -> f16 dense convert, 6 slices in one launch ----------------
__global__ __launch_bounds__(256) void cvt_f16(
    const float* __restrict__ s0, const float* __restrict__ s1, const float* __restrict__ s2,
    const float* __restrict__ s3, const float* __restrict__ s4, const float* __restrict__ s5,
    _Float16* __restrict__ d0, _Float16* __restrict__ d1, _Float16* __restrict__ d2,
    _Float16* __restrict__ d3, _Float16* __restrict__ d4, _Float16* __restrict__ d5)
{
  const int z = blockIdx.y;
  const float* s = z == 0 ? s0 : z == 1 ? s1 : z == 2 ? s2 : z == 3 ? s3 : z == 4 ? s4 : s5;
  _Float16* d = z == 0 ? d0 : z == 1 ? d1 : z == 2 ? d2 : z == 3 ? d3 : z == 4 ? d4 : d5;
  const int n4 = DM * DM / 4;
  for (int v = blockIdx.x * blockDim.x + threadIdx.x; v < n4;
       v += gridDim.x * blockDim.x) {
    float4 x = ((const float4*)s)[v];
    half4v h = { (_Float16)x.x, (_Float16)x.y, (_Float16)x.z, (_Float16)x.w };
    ((half4v*)d)[v] = h;
  }
}

// single-matrix variant for wo (runs after attn; Qp region becomes free)
__global__ __launch_bounds__(256) void cvt_f16_one(
    const float* __restrict__ s, _Float16* __restrict__ d)
{
  const int n4 = DM * DM / 4;
  for (int v = blockIdx.x * blockDim.x + threadIdx.x; v < n4;
       v += gridDim.x * blockDim.x) {
    float4 x = ((const float4*)s)[v];
    half4v h = { (_Float16)x.x, (_Float16)x.y, (_Float16)x.z, (_Float16)x.w };
    ((half4v*)d)[v] = h;
  }
}

// ---------------- cached K fp32 -> f16 linear convert ----------------
__global__ __launch_bounds__(256) void convert_K(
    const float* __restrict__ ck, _Float16* __restrict__ K)
{
  const long long nvec = (long long)NB * CL * DM / 4;
  const int pb = CL * DM / 4;
  for (long long v = (long long)blockIdx.x * blockDim.x + threadIdx.x; v < nvec;
       v += (long long)gridDim.x * blockDim.x) {
    int b = (int)(v / pb);
    long long r = v - (long long)b * pb;
    float4 x = ((const float4*)ck)[v];
    half4v hx = { (_Float16)x.x, (_Float16)x.y, (_Float16)x.z, (_Float16)x.w };
    ((half4v*)K)[(long long)b * (TT * DM / 4) + r] = hx;
  }
}

// ---------------- FUSED: QKV GEMM (bid<768) + cached-V transpose (bid>=768) ----------------
// GEMM: 128x128 tile, BK=32, 8 waves, gl_lds staging (R4-proven structure).
// transV: 512-thr block transposes 64t x 128dm of cv into Vt[b][h][d][t].
// Overlap rationale: GEMM is MFMA-bound/low-BW, transV is BW-bound/no-compute.
__global__ __launch_bounds__(512) void fused_pre(
    const _Float16* __restrict__ A0, const _Float16* __restrict__ A1,
    const _Float16* __restrict__ A2,
    const _Float16* __restrict__ W0, const _Float16* __restrict__ W1,
    const _Float16* __restrict__ W2,
    const float* __restrict__ b0, const float* __restrict__ b1,
    const float* __restrict__ b2,
    _Float16* __restrict__ Qp, _Float16* __restrict__ Kc,
    _Float16* __restrict__ Vt, const float* __restrict__ cv)
{
  __shared__ __align__(16) char smem[4 * 8192];

  const int bid = blockIdx.x;
  const int tid = threadIdx.x;

  if (bid < 768) {
    // ---------------- QKV GEMM ----------------
    char* Abuf = smem;
    char* Wbuf = smem + 2 * 8192;
    const int bm = bid & 15, bn = (bid >> 4) & 15, z = bid >> 8;
    const _Float16* Ain = z == 0 ? A0 : z == 1 ? A1 : A2;
    const _Float16* W   = z == 0 ? W0 : z == 1 ? W1 : W2;
    const float* bias   = z == 0 ? b0 : z == 1 ? b1 : b2;

    const int wid = tid >> 6, lane = tid & 63;
    const int wm = wid >> 2, wn = wid & 3;
    const int lr = lane & 15, lg = lane >> 4;

    f32x4 acc[4][2];
#pragma unroll
    for (int i = 0; i < 4; ++i)
#pragma unroll
      for (int j = 0; j < 2; ++j) acc[i][j] = (f32x4){0.f, 0.f, 0.f, 0.f};

    size_t aoff, woff;
    {
      const int o = wid * 1024 + lane * 16;
      const int prow = o >> 7, pb = o & 127;
      const int lb = pb ^ ((prow & 7) << 4);
      const int r = (prow << 1) | (lb >> 6), c = lb & 63;
      aoff = (size_t)(bm * 128 + r) * 4096 + c;
      woff = (size_t)(bn * 128 + r) * 4096 + c;
    }

    auto stage = [&](int kt, int buf) {
      gl_lds16((const char*)Ain + aoff + kt * 64, Abuf + buf * 8192 + wid * 1024);
      gl_lds16((const char*)W + woff + kt * 64, Wbuf + buf * 8192 + wid * 1024);
    };
    auto lds_addr = [](const char* base, int r, int cb) -> const char* {
      return base + ((r >> 1) << 7) + ((((r & 1) << 6) | cb) ^ (((r >> 1) & 7) << 4));
    };
    auto compute = [&](int buf) {
      const char* ab = Abuf + buf * 8192;
      const char* wb = Wbuf + buf * 8192;
      half8 af[4], bf[2];
#pragma unroll
      for (int i = 0; i < 4; ++i)
        af[i] = *(const half8*)lds_addr(ab, wm * 64 + i * 16 + lr, lg << 4);
#pragma unroll
      for (int j = 0; j < 2; ++j)
        bf[j] = *(const half8*)lds_addr(wb, wn * 32 + j * 16 + lr, lg << 4);
#pragma unroll
      for (int i = 0; i < 4; ++i)
#pragma unroll
        for (int j = 0; j < 2; ++j)
          acc[i][j] = __builtin_amdgcn_mfma_f32_16x16x32_f16(af[i], bf[j], acc[i][j], 0, 0, 0);
    };

    const int NKT = DM / 32;
    stage(0, 0);
    __syncthreads();
    for (int kt = 0; kt < NKT; ++kt) {
      if (kt + 1 < NKT) stage(kt + 1, (kt + 1) & 1);
      compute(kt & 1);
      __syncthreads();
    }

    const float qscale = 0.08838834764831845f * 1.4426950408889634f;
#pragma unroll
    for (int i = 0; i < 4; ++i) {
      const int m0 = bm * 128 + wm * 64 + i * 16 + lg * 4;
#pragma unroll
      for (int j = 0; j < 2; ++j) {
        const int gn = bn * 128 + wn * 32 + j * 16 + lr;
        const float bb = bias[gn];
        if (z == 0) {
#pragma unroll
          for (int r = 0; r < 4; ++r)
            Qp[(size_t)(m0 + r) * DM + gn] = (_Float16)((acc[i][j][r] + bb) * qscale);
        } else if (z == 1) {
          const int b = m0 >> 9;
#pragma unroll
          for (int r = 0; r < 4; ++r)
            Kc[((size_t)b * TT + CL + ((m0 + r) & 511)) * DM + gn] =
                (_Float16)(acc[i][j][r] + bb);
        } else {
          half4v hv;
#pragma unroll
          for (int r = 0; r < 4; ++r) hv[r] = (_Float16)(acc[i][j][r] + bb);
          const int b = m0 >> 9, t = CL + (m0 & 511);
          const int h = gn >> 7, d = gn & 127;
          *(half4v*)&Vt[((size_t)(b * NH + h) * DH + d) * TT + t] = hv;
        }
      }
    }
  } else {
    // ---------------- cached V transpose: 64t x 128dm tile ----------------
    _Float16 (*T)[136] = (_Float16(*)[136])smem;   // 64 x 136 halves = 17.4 KB
    const int tv = bid - 768;              // 0..3583
    const int b = tv / 896;
    const int rem = tv - b * 896;
    const int t0 = (rem % 56) * 64;
    const int dm0 = (rem / 56) * 128;
    {
      const int tr = tid >> 3, c0 = (tid & 7) * 16;
      const float* src = cv + ((size_t)b * CL + t0 + tr) * DM + dm0 + c0;
      float4 a0 = ((const float4*)src)[0];
      float4 a1 = ((const float4*)src)[1];
      float4 a2 = ((const float4*)src)[2];
      float4 a3 = ((const float4*)src)[3];
      half8 h0 = { (_Float16)a0.x, (_Float16)a0.y, (_Float16)a0.z, (_Float16)a0.w,
                   (_Float16)a1.x, (_Float16)a1.y, (_Float16)a1.z, (_Float16)a1.w };
      half8 h1 = { (_Float16)a2.x, (_Float16)a2.y, (_Float16)a2.z, (_Float16)a2.w,
                   (_Float16)a3.x, (_Float16)a3.y, (_Float16)a3.z, (_Float16)a3.w };
      *(half8*)&T[tr][c0] = h0;
      *(half8*)&T[tr][c0 + 8] = h1;
    }
    __syncthreads();
    {
      const int dl = tid >> 2, tc = (tid & 3) * 16;
      const int h = dm0 >> 7;
      half8 o0, o1;
#pragma unroll
      for (int i = 0; i < 8; ++i) o0[i] = T[tc + i][dl];
#pragma unroll
      for (int i = 0; i < 8; ++i) o1[i] = T[tc + 8 + i][dl];
      _Float16* dst = Vt + ((size_t)(b * NH + h) * DH + dl) * TT + t0 + tc;
      *(half8*)dst = o0;
      *(half8*)(dst + 8) = o1;
    }
  }
}

// ---------------- O-projection GEMM (f16 A via gl_lds, fp32 out) ----------------
__global__ __launch_bounds__(512, 4) void mm16o(
    const _Float16* __restrict__ Ain, const _Float16* __restrict__ W,
    const float* __restrict__ bias, float* __restrict__ Co)
{
  __shared__ __align__(16) char smem[4 * 8192];
  char* Abuf = smem;
  char* Wbuf = smem + 2 * 8192;

  const int tid = threadIdx.x;
  const int bm = blockIdx.x, bn = blockIdx.y;
  const int wid = tid >> 6, lane = tid & 63;
  const int wm = wid >> 2, wn = wid & 3;
  const int lr = lane & 15, lg = lane >> 4;

  f32x4 acc[4][2];
#pragma unroll
  for (int i = 0; i < 4; ++i)
#pragma unroll
    for (int j = 0; j < 2; ++j) acc[i][j] = (f32x4){0.f, 0.f, 0.f, 0.f};

  size_t aoff, woff;
  {
    const int o = wid * 1024 + lane * 16;
    const int prow = o >> 7, pb = o & 127;
    const int lb = pb ^ ((prow & 7) << 4);
    const int r = (prow << 1) | (lb >> 6), c = lb & 63;
    aoff = (size_t)(bm * 128 + r) * 4096 + c;
    woff = (size_t)(bn * 128 + r) * 4096 + c;
  }

  auto stage = [&](int kt, int buf) {
    gl_lds16((const char*)Ain + aoff + kt * 64, Abuf + buf * 8192 + wid * 1024);
    gl_lds16((const char*)W + woff + kt * 64, Wbuf + buf * 8192 + wid * 1024);
  };
  auto lds_addr = [](const char* base, int r, int cb) -> const char* {
    return base + ((r >> 1) << 7) + ((((r & 1) << 6) | cb) ^ (((r >> 1) & 7) << 4));
  };
  auto compute = [&](int buf) {
    const char* ab = Abuf + buf * 8192;
    const char* wb = Wbuf + buf * 8192;
    half8 af[4], bf[2];
#pragma unroll
    for (int i = 0; i < 4; ++i)
      af[i] = *(const half8*)lds_addr(ab, wm * 64 + i * 16 + lr, lg << 4);
#pragma unroll
    for (int j = 0; j < 2; ++j)
      bf[j] = *(const half8*)lds_addr(wb, wn * 32 + j * 16 + lr, lg << 4);
#pragma unroll
    for (int i = 0; i < 4; ++i)
#pragma unroll
      for (int j = 0; j < 2; ++j)
        acc[i][j] = __builtin_amdgcn_mfma_f32_16x16x32_f16(af[i], bf[j], acc[i][j], 0, 0, 0);
  };

  const int NKT = DM / 32;
  stage(0, 0);
  __syncthreads();
  for (int kt = 0; kt < NKT; ++kt) {
    if (kt + 1 < NKT) stage(kt + 1, (kt + 1) & 1);
    compute(kt & 1);
    __syncthreads();
  }

#pragma unroll
  for (int i = 0; i < 4; ++i) {
    const int m0 = bm * 128 + wm * 64 + i * 16 + lg * 4;
#pragma unroll
    for (int j = 0; j < 2; ++j) {
      const int gn = bn * 128 + wn * 32 + j * 16 + lr;
      const float bb = bias[gn];
#pragma unroll
      for (int r = 0; r < 4; ++r)
        Co[(size_t)(m0 + r) * DM + gn] = acc[i][j][r] + bb;
    }
  }
}

// ---------------- flash attention (R8 structure, no setprio, gated mask) ----------------
// 256 blocks, 512 threads = 8 waves x 32 q rows = 256 q/block; KVB=64; kv-split x2.
// K dbuf (32KB) + V tribuf (48KB) + P (32KB) = 112KB LDS, 1 block/CU.
// Pipelined: iter t does qk(t) [MFMA] || softmax(t-1)+pv(t-1).
__global__ __launch_bounds__(512) void attn_kernel(
    const _Float16* __restrict__ Qp, const _Float16* __restrict__ Kc,
    const _Float16* __restrict__ Vt, _Float16* __restrict__ O0,
    _Float16* __restrict__ O1, float2* __restrict__ ml)
{
  __shared__ _Float16 Ks[2][64 * 128];
  __shared__ _Float16 VTs[3][128 * 64];
  __shared__ _Float16 Ps[8][32 * 64];

  const int tid = threadIdx.x;
  const int lin = blockIdx.x;
  const int xcd = lin & 7, slot = lin >> 3;
  const int pair = xcd * 8 + (slot >> 2);
  const int rem = slot & 3;
  const int qb = rem >> 1, part = rem & 1;
  const int b = pair >> 4, h = pair & 15;

  const int wid = tid >> 6, lane = tid & 63;
  const int lr = lane & 15, lg = lane >> 4;
  const int qw = qb * 256 + wid * 32;

  half8 qf[2][4];
#pragma unroll
  for (int qs = 0; qs < 2; ++qs)
#pragma unroll
    for (int kk = 0; kk < 4; ++kk)
      qf[qs][kk] = *(const half8*)&Qp[(size_t)(b * SQ + qw + qs * 16 + lr) * DM +
                                      h * DH + kk * 32 + lg * 8];

  f32x4 zero = {0.f, 0.f, 0.f, 0.f};
  f32x4 acc[8][2];
#pragma unroll
  for (int d = 0; d < 8; ++d)
#pragma unroll
    for (int qs = 0; qs < 2; ++qs) acc[d][qs] = zero;
  float m_run[2] = {-1e30f, -1e30f}, l_run[2] = {0.f, 0.f};

  const int nt_full = (CL + qb * 256 + 256) / 64;
  const int halfn = nt_full >> 1;
  const int tbeg = part ? halfn : 0;
  const int nt = part ? (nt_full - halfn) : halfn;

  int ksrc[2], vsrc[2];
#pragma unroll
  for (int c = 0; c < 2; ++c) {
    const int p = c * 512 + wid * 64 + lane;
    { const int r = p >> 4, pg = p & 15, gc = pg ^ (r & 7);
      ksrc[c] = r * DM + gc * 8; }
    { const int d = p >> 3, pg = p & 7, gt = pg ^ (d & 7);
      vsrc[c] = d * TT + gt * 8; }
  }
  const _Float16* Kb = Kc + (size_t)b * TT * DM + h * DH;
  const _Float16* Vb = Vt + (size_t)(b * NH + h) * DH * TT;

  auto stage = [&](int tt, int kbuf, int vbuf) {
    const int t0 = (tbeg + tt) * 64;
#pragma unroll
    for (int c = 0; c < 2; ++c)
      gl_lds16(Kb + (size_t)t0 * DM + ksrc[c], &Ks[kbuf][(c * 512 + wid * 64) * 8]);
#pragma unroll
    for (int c = 0; c < 2; ++c)
      gl_lds16(Vb + t0 + vsrc[c], &VTs[vbuf][(c * 512 + wid * 64) * 8]);
  };

  auto qk = [&](int kbuf, f32x4 (*s)[2]) {
#pragma unroll
    for (int j = 0; j < 4; ++j)
#pragma unroll
      for (int qs = 0; qs < 2; ++qs) s[j][qs] = zero;
#pragma unroll
    for (int kk = 0; kk < 4; ++kk)
#pragma unroll
      for (int j = 0; j < 4; ++j) {
        half8 kb = *(const half8*)&Ks[kbuf][KSW(j * 16 + lr, kk * 32 + lg * 8)];
        s[j][0] = __builtin_amdgcn_mfma_f32_16x16x32_f16(kb, qf[0][kk], s[j][0], 0, 0, 0);
        s[j][1] = __builtin_amdgcn_mfma_f32_16x16x32_f16(kb, qf[1][kk], s[j][1], 0, 0, 0);
      }
  };

  auto mask_s = [&](int t0, f32x4 (*s)[2]) {
    if (part && t0 + 63 > CL + qw) {
#pragma unroll
      for (int j = 0; j < 4; ++j)
#pragma unroll
        for (int qs = 0; qs < 2; ++qs)
#pragma unroll
          for (int r = 0; r < 4; ++r)
            if (t0 + j * 16 + lg * 4 + r > CL + qw + qs * 16 + lr) s[j][qs][r] = -1e30f;
    }
  };

  auto softmax_step = [&](f32x4 (*s)[2]) {
    float mt[2];
#pragma unroll
    for (int qs = 0; qs < 2; ++qs) {
      float m = s[0][qs][0];
#pragma unroll
      for (int j = 0; j < 4; ++j)
#pragma unroll
        for (int r = 0; r < 4; ++r) m = fmaxf(m, s[j][qs][r]);
      mt[qs] = m;
    }
    if (!__all(mt[0] <= m_run[0] + 10.0f && mt[1] <= m_run[1] + 10.0f)) {
#pragma unroll
      for (int qs = 0; qs < 2; ++qs) {
        float m = fmaxf(mt[qs], __shfl_xor(mt[qs], 16));
        m = fmaxf(m, __shfl_xor(m, 32));
        const float mn = fmaxf(m_run[qs], m);
        const float fsc = exp2f(m_run[qs] - mn);
        m_run[qs] = mn;
        l_run[qs] *= fsc;
#pragma unroll
        for (int d = 0; d < 8; ++d)
#pragma unroll
          for (int r = 0; r < 4; ++r) acc[d][qs][r] *= fsc;
      }
    }
#pragma unroll
    for (int qs = 0; qs < 2; ++qs) {
      float ps = 0.f;
#pragma unroll
      for (int j = 0; j < 4; ++j) {
        float p0 = exp2f(s[j][qs][0] - m_run[qs]);
        float p1 = exp2f(s[j][qs][1] - m_run[qs]);
        float p2 = exp2f(s[j][qs][2] - m_run[qs]);
        float p3 = exp2f(s[j][qs][3] - m_run[qs]);
        ps += (p0 + p1) + (p2 + p3);
        half4v hp = { (_Float16)p0, (_Float16)p1, (_Float16)p2, (_Float16)p3 };
        *(half4v*)&Ps[wid][PSW(qs * 16 + lr, j * 16 + lg * 4)] = hp;
      }
      l_run[qs] += ps;
    }
  };

  auto pv = [&](int vbuf) {
#pragma unroll
    for (int kk = 0; kk < 2; ++kk) {
      half8 pf0 = *(const half8*)&Ps[wid][PSW(lr, kk * 32 + lg * 8)];
      half8 pf1 = *(const half8*)&Ps[wid][PSW(16 + lr, kk * 32 + lg * 8)];
#pragma unroll
      for (int d = 0; d < 8; ++d) {
        half8 vf = *(const half8*)&VTs[vbuf][VSW(d * 16 + lr, kk * 32 + lg * 8)];
        acc[d][0] = __builtin_amdgcn_mfma_f32_16x16x32_f16(vf, pf0, acc[d][0], 0, 0, 0);
        acc[d][1] = __builtin_amdgcn_mfma_f32_16x16x32_f16(vf, pf1, acc[d][1], 0, 0, 0);
      }
    }
  };

  f32x4 sp[4][2], sc[4][2];

  stage(0, 0, 0);
  __syncthreads();
  stage(1, 1, 1);
  qk(0, sp);
  mask_s(tbeg * 64, sp);

  for (int t = 1; t < nt; ++t) {
    __syncthreads();
    if (t + 1 < nt) stage(t + 1, (t + 1) & 1, (t + 1) % 3);
    qk(t & 1, sc);
    softmax_step(sp);
    pv((t - 1) % 3);
    mask_s((tbeg + t) * 64, sc);
#pragma unroll
    for (int j = 0; j < 4; ++j)
#pragma unroll
      for (int qs = 0; qs < 2; ++qs) sp[j][qs] = sc[j][qs];
  }
  softmax_step(sp);
  pv((nt - 1) % 3);

  _Float16* Od = part ? O1 : O0;
#pragma unroll
  for (int qs = 0; qs < 2; ++qs) {
    float lt = l_run[qs] + __shfl_xor(l_run[qs], 16);
    lt += __shfl_xor(lt, 32);
    const float inv = 1.0f / lt;
#pragma unroll
    for (int d = 0; d < 8; ++d) {
      half4v hv;
#pragma unroll
      for (int r = 0; r < 4; ++r) hv[r] = (_Float16)(acc[d][qs][r] * inv);
      *(half4v*)&Od[(size_t)(b * SQ + qw + qs * 16 + lr) * DM + h * DH + d * 16 + lg * 4] = hv;
    }
    if (lg == 0) {
      float2 e; e.x = m_run[qs]; e.y = lt;
      ml[part * (64 * SQ) + ((b * NH + h) * SQ) + qw + qs * 16 + lr] = e;
    }
  }
}

// ---------------- combine the two kv-partitions ----------------
__global__ __launch_bounds__(256) void combine(
    _Float16* __restrict__ AO, const _Float16* __restrict__ O1,
    const float2* __restrict__ ml)
{
  const int idx = blockIdx.x * 256 + threadIdx.x;
  const int row = idx >> 8;
  const int col0 = (idx & 255) * 8;
  const int b = row >> 9, q = row & 511, h = col0 >> 7;
  const float2 e0 = ml[(b * NH + h) * SQ + q];
  const float2 e1 = ml[64 * SQ + (b * NH + h) * SQ + q];
  const float m = fmaxf(e0.x, e1.x);
  float w0 = e0.y * exp2f(e0.x - m);
  float w1 = e1.y * exp2f(e1.x - m);
  const float inv = 1.0f / (w0 + w1);
  w0 *= inv; w1 *= inv;
  const size_t o = (size_t)row * DM + col0;
  half8 a = *(const half8*)&AO[o];
  half8 c = *(const half8*)&O1[o];
  half8 r;
#pragma unroll
  for (int i = 0; i < 8; ++i)
    r[i] = (_Float16)(w0 * (float)a[i] + w1 * (float)c[i]);
  *(half8*)&AO[o] = r;
}

extern "C" void kernel_launch(void* const* d_in, const int* in_sizes, int n_in,
                              void* d_out, int out_size, void* d_ws, size_t ws_size,
                              hipStream_t stream) {
  const float* query = (const float*)d_in[0];
  const float* key   = (const float*)d_in[1];
  const float* value = (const float*)d_in[2];
  const float* ck    = (const float*)d_in[3];
  const float* cv    = (const float*)d_in[4];
  const float* wq = (const float*)d_in[5];
  const float* bq = (const float*)d_in[6];
  const float* wk = (const float*)d_in[7];
  const float* bk = (const float*)d_in[8];
  const float* wv = (const float*)d_in[9];
  const float* bv = (const float*)d_in[10];
  const float* wo = (const float*)d_in[11];
  const float* bo = (const float*)d_in[12];

  char* ws = (char*)d_ws;
  _Float16* Kc = (_Float16*)ws;                 // 64 MiB: [4][4096][2048]
  _Float16* Vt = (_Float16*)(ws + 67108864);    // 64 MiB: [4][16][128][4096]
  _Float16* Qp = (_Float16*)(ws + 134217728);   // 8 MiB
  _Float16* AO = (_Float16*)(ws + 142606336);   // 8 MiB

  // Scratch staging (all dead at their next writer):
  // qh in AO (attn writes AO later); kh/vh in d_out (attn writes O1s/mls later);
  // wq/wk/wv f16 inside Kc CACHE stripes (t<3584) of b0/b1/b2 — disjoint from
  // GEMM's K-scatter (t>=3584); convert_K overwrites them afterwards.
  _Float16* qh = AO;
  _Float16* kh = (_Float16*)d_out;                       // 8 MiB
  _Float16* vh = (_Float16*)((char*)d_out + 8388608);    // 8 MiB
  _Float16* wqh = Kc;                                    // b0 cache stripe
  _Float16* wkh = (_Float16*)(ws + 16777216);            // b1 cache stripe
  _Float16* wvh = (_Float16*)(ws + 33554432);            // b2 cache stripe
  _Float16* woh = Qp;

  // post-attn scratch in d_out (kh/vh dead by then)
  _Float16* O1s = (_Float16*)d_out;                // 8 MiB
  float2* mls = (float2*)((char*)d_out + 8388608); // 512 KiB

  cvt_f16<<<dim3(512, 6), 256, 0, stream>>>(
      query, key, value, wq, wk, wv, qh, kh, vh, wqh, wkh, wvh);
  fused_pre<<<768 + 3584, 512, 0, stream>>>(
      qh, kh, vh, wqh, wkh, wvh, bq, bk, bv, Qp, Kc, Vt, cv);
  convert_K<<<2048, 256, 0, stream>>>(ck, Kc);
  attn_kernel<<<256, 512, 0, stream>>>(Qp, Kc, Vt, AO, O1s, mls);
  combine<<<2048, 256, 0, stream>>>(AO, O1s, mls);
  cvt_f16_one<<<512, 256, 0, stream>>>(wo, woh);
  mm16o<<<dim3(16, 16), 512, 0, stream>>>(AO, woh, bo, (float*)d_out);
}